// Round 7
// baseline (78.707 us; speedup 1.0000x reference)
//
#include <hip/hip_runtime.h>
#include <hip/hip_bf16.h>
#include <math.h>

#define B_ROWS 4096
#define NTOT   8192
#define DDIM   256
#define CSCALE 1.6986436f      // sqrt(2*log2(e)); zn scaled so A.B = 2*log2(e)*cos
#define NPART  8

typedef __attribute__((ext_vector_type(8))) short short8;   // 8 bf16
typedef __attribute__((ext_vector_type(4))) float f32x4;

static __device__ inline unsigned short f2bf(float x) {
    union { float f; unsigned u; } v; v.f = x;
    unsigned r = v.u + 0x7fffu + ((v.u >> 16) & 1u);  // RNE
    return (unsigned short)(r >> 16);
}

// ---- kernel 1: fused normalize (scaled bf16) + positive-pair sims + partials zeroing ----
__global__ __launch_bounds__(256) void norm_kernel(
        const float* __restrict__ zi, const float* __restrict__ zj,
        unsigned short* __restrict__ zn, float* __restrict__ simpos,
        float* __restrict__ parts) {
    int pair = blockIdx.x * 4 + (threadIdx.x >> 6);
    int lane = threadIdx.x & 63;
    float4 vi = reinterpret_cast<const float4*>(zi + (size_t)pair * DDIM)[lane];
    float4 vj = reinterpret_cast<const float4*>(zj + (size_t)pair * DDIM)[lane];
    float ssi = vi.x*vi.x + vi.y*vi.y + vi.z*vi.z + vi.w*vi.w;
    float ssj = vj.x*vj.x + vj.y*vj.y + vj.z*vj.z + vj.w*vj.w;
    float dij = vi.x*vj.x + vi.y*vj.y + vi.z*vj.z + vi.w*vj.w;
    #pragma unroll
    for (int o = 32; o > 0; o >>= 1) {
        ssi += __shfl_xor(ssi, o);
        ssj += __shfl_xor(ssj, o);
        dij += __shfl_xor(dij, o);
    }
    float invi = 1.0f / fmaxf(sqrtf(ssi), 1e-8f);
    float invj = 1.0f / fmaxf(sqrtf(ssj), 1e-8f);
    float si = CSCALE * invi, sj = CSCALE * invj;
    ushort4 hi4, hj4;
    hi4.x = f2bf(vi.x * si); hi4.y = f2bf(vi.y * si);
    hi4.z = f2bf(vi.z * si); hi4.w = f2bf(vi.w * si);
    hj4.x = f2bf(vj.x * sj); hj4.y = f2bf(vj.y * sj);
    hj4.z = f2bf(vj.z * sj); hj4.w = f2bf(vj.w * sj);
    *reinterpret_cast<ushort4*>(zn + (size_t)pair * DDIM + lane * 4) = hi4;
    *reinterpret_cast<ushort4*>(zn + (size_t)(pair + B_ROWS) * DDIM + lane * 4) = hj4;
    if (lane == 0) simpos[pair] = 2.0f * dij * invi * invj;   // logits = cos/tau
    if (blockIdx.x < 256) parts[blockIdx.x * 256 + threadIdx.x] = 0.0f;  // zero 64K floats
}

// ---- kernel 2 body: 128 rows x 128 cols (2 x 64-col units), fully static ----
// 4 waves x 32 A-rows as 2 rowsets of 16 (a[2][8] = 64 VGPR). 16x16x32 MFMA:
// per subtile TWO independent 8-deep acc chains sharing each B-frag (ILP x2).
template<bool CROSS>
static __device__ __forceinline__ void sim_body(
        const unsigned short* __restrict__ zn, float* __restrict__ part,
        unsigned char* __restrict__ tile, float (* __restrict__ csum_lds)[128],
        int waveRow, int c0base) {
    int tid  = threadIdx.x;
    int wid  = tid >> 6;
    int lane = tid & 63;
    int l15  = lane & 15;
    int l4   = lane >> 4;

    // A fragments (16x16x32 layout: row = l15, k = m*32 + l4*8)
    short8 a[2][8];
    #pragma unroll
    for (int rs = 0; rs < 2; ++rs) {
        const unsigned short* ap = zn + (size_t)(waveRow + rs * 16 + l15) * DDIM;
        #pragma unroll
        for (int m = 0; m < 8; ++m)
            a[rs][m] = *reinterpret_cast<const short8*>(ap + m * 32 + l4 * 8);
    }

    float rsum[2][4] = {{0.f,0.f,0.f,0.f},{0.f,0.f,0.f,0.f}};

    #pragma unroll
    for (int ui = 0; ui < 2; ++ui) {
        int c0 = c0base + ui * 64;
        __syncthreads();   // protect tile before overwrite
        // stage 64 cols x 256 K bf16 = 32 KB, 4-bit XOR swizzle (ck ^ row&15);
        // two passes of 4 loads to cap in-flight register pressure.
        #pragma unroll
        for (int g = 0; g < 2; ++g) {
            uint4 t[4];
            #pragma unroll
            for (int p = 0; p < 4; ++p) {
                int id = (g * 4 + p) * 256 + tid;
                int tr = id >> 5, ck = id & 31;
                t[p] = *reinterpret_cast<const uint4*>(
                    zn + (size_t)(c0 + tr) * DDIM + ck * 8);
            }
            #pragma unroll
            for (int p = 0; p < 4; ++p) {
                int id = (g * 4 + p) * 256 + tid;
                int tr = id >> 5, ck = id & 31;
                *reinterpret_cast<uint4*>(tile + tr * 512 + ((ck ^ (tr & 15)) << 4)) = t[p];
            }
        }
        __syncthreads();

        #pragma unroll
        for (int sub = 0; sub < 4; ++sub) {
            // B row (= col) for this lane: sub*16 + l15; (row&15) == l15
            const unsigned char* bbase = tile + (size_t)(sub * 16 + l15) * 512;
            f32x4 acc0 = {0.f,0.f,0.f,0.f}, acc1 = {0.f,0.f,0.f,0.f};
            #pragma unroll
            for (int m = 0; m < 8; ++m) {
                short8 bf = *reinterpret_cast<const short8*>(
                    bbase + (((4 * m + l4) ^ l15) << 4));
                acc0 = __builtin_amdgcn_mfma_f32_16x16x32_bf16(a[0][m], bf, acc0, 0, 0, 0);
                acc1 = __builtin_amdgcn_mfma_f32_16x16x32_bf16(a[1][m], bf, acc1, 0, 0, 0);
            }
            int gcol = c0 + sub * 16 + l15;
            float cs = 0.0f;
            #pragma unroll
            for (int j = 0; j < 4; ++j) {
                float e0 = exp2f(acc0[j]);   // zn pre-scaled: acc = 2*log2e*cos
                float e1 = exp2f(acc1[j]);
                if (CROSS) {
                    int g0 = waveRow + l4 * 4 + j;        // rowset 0
                    e0 = (gcol > g0) ? e0 : 0.0f;
                    e1 = (gcol > g0 + 16) ? e1 : 0.0f;    // rowset 1
                }
                rsum[0][j] += e0;
                rsum[1][j] += e1;
                cs += e0 + e1;
            }
            cs += __shfl_xor(cs, 16);
            cs += __shfl_xor(cs, 32);
            if (lane < 16) csum_lds[wid][ui * 64 + sub * 16 + l15] = cs;
        }
    }

    // ---- flush rows: reduce across the 16 col-lanes, one atomic per row ----
    #pragma unroll
    for (int rs = 0; rs < 2; ++rs)
        #pragma unroll
        for (int j = 0; j < 4; ++j) {
            float s = rsum[rs][j];
            #pragma unroll
            for (int m = 8; m >= 1; m >>= 1) s += __shfl_xor(s, m);
            if (l15 == 0)
                atomicAdd(&part[waveRow + rs * 16 + l4 * 4 + j], s);
        }

    // ---- flush cols: sum 4 waves' slices, one atomic per col ----
    __syncthreads();
    if (tid < 128) {
        float s = csum_lds[0][tid] + csum_lds[1][tid]
                + csum_lds[2][tid] + csum_lds[3][tid];
        atomicAdd(&part[c0base + tid], s);
    }
}

// 2080 uniform blocks: strip s (64 strips of 128 rows) has 64-s blocks of 128
// cols starting at the diagonal; prefix(s) = 64s - s(s-1)/2. rel==0 => CROSS.
__global__ __launch_bounds__(256, 4) void sim_kernel(
        const unsigned short* __restrict__ zn, float* __restrict__ parts) {
    __shared__ __align__(16) unsigned char tile[64 * 512];   // 32 KB
    __shared__ float csum_lds[4][128];                       // 2 KB

    int b = blockIdx.x;
    int s = (int)(64.5f - sqrtf(4160.25f - 2.0f * (float)b));
    if (s < 0) s = 0;
    if (s > 63) s = 63;
    while (s > 0 && b < 64 * s - (s * (s - 1)) / 2) --s;
    while (b >= 64 * (s + 1) - ((s + 1) * s) / 2) ++s;
    int rel = b - (64 * s - (s * (s - 1)) / 2);

    int waveRow = s * 128 + (threadIdx.x >> 6) * 32;
    int c0base  = (s + rel) * 128;
    float* part = parts + (size_t)(b & (NPART - 1)) * NTOT;

    if (rel == 0) sim_body<true >(zn, part, tile, csum_lds, waveRow, c0base);
    else          sim_body<false>(zn, part, tile, csum_lds, waveRow, c0base);
}

// ---- kernel 3: loss partials; out zeroed by memset, atomicAdd final ----
__global__ __launch_bounds__(256) void finalize_kernel(
        const float* __restrict__ parts, const float* __restrict__ simpos,
        float* __restrict__ out) {
    __shared__ float red[4];
    int r = blockIdx.x * 512 + threadIdx.x;
    float acc = 0.0f;
    #pragma unroll
    for (int rr = 0; rr < 2; ++rr, r += 256) {
        float s = 0.0f;
        #pragma unroll
        for (int p = 0; p < NPART; ++p) s += parts[p * NTOT + r];
        acc += logf(s) - simpos[r & (B_ROWS - 1)];
    }
    #pragma unroll
    for (int o = 32; o > 0; o >>= 1) acc += __shfl_xor(acc, o);
    if ((threadIdx.x & 63) == 0) red[threadIdx.x >> 6] = acc;
    __syncthreads();
    if (threadIdx.x == 0)
        atomicAdd(out, (red[0] + red[1] + red[2] + red[3]) / (float)NTOT);
}

extern "C" void kernel_launch(void* const* d_in, const int* in_sizes, int n_in,
                              void* d_out, int out_size, void* d_ws, size_t ws_size,
                              hipStream_t stream) {
    const float* zi = (const float*)d_in[0];
    const float* zj = (const float*)d_in[1];
    float* out = (float*)d_out;

    unsigned short* zn = (unsigned short*)d_ws;                        // 4 MB
    float* parts  = (float*)((char*)d_ws + (size_t)NTOT * DDIM * 2);   // 256 KB
    float* simpos = parts + NPART * NTOT;                              // 16 KB

    hipMemsetAsync(out, 0, sizeof(float), stream);
    norm_kernel<<<B_ROWS / 4, 256, 0, stream>>>(zi, zj, zn, simpos, parts);
    sim_kernel<<<2080, 256, 0, stream>>>(zn, parts);
    finalize_kernel<<<16, 256, 0, stream>>>(parts, simpos, out);
}

// Round 8
// 60.838 us; speedup vs baseline: 1.2937x; 1.2937x over previous
//
#include <hip/hip_runtime.h>
#include <hip/hip_bf16.h>
#include <math.h>

#define B_ROWS 4096
#define NTOT   8192
#define DDIM   256
#define CSCALE 1.6986436f      // sqrt(2*log2(e)); zn scaled so A.B = 2*log2(e)*cos
#define NPART  8

typedef __attribute__((ext_vector_type(8))) short short8;   // 8 bf16
typedef __attribute__((ext_vector_type(4))) float f32x4;

static __device__ inline unsigned short f2bf(float x) {
    union { float f; unsigned u; } v; v.f = x;
    unsigned r = v.u + 0x7fffu + ((v.u >> 16) & 1u);  // RNE
    return (unsigned short)(r >> 16);
}

// ---- kernel 1: fused normalize (scaled bf16) + positive-pair sims + partials zeroing ----
__global__ __launch_bounds__(256) void norm_kernel(
        const float* __restrict__ zi, const float* __restrict__ zj,
        unsigned short* __restrict__ zn, float* __restrict__ simpos,
        float* __restrict__ parts) {
    int pair = blockIdx.x * 4 + (threadIdx.x >> 6);
    int lane = threadIdx.x & 63;
    float4 vi = reinterpret_cast<const float4*>(zi + (size_t)pair * DDIM)[lane];
    float4 vj = reinterpret_cast<const float4*>(zj + (size_t)pair * DDIM)[lane];
    float ssi = vi.x*vi.x + vi.y*vi.y + vi.z*vi.z + vi.w*vi.w;
    float ssj = vj.x*vj.x + vj.y*vj.y + vj.z*vj.z + vj.w*vj.w;
    float dij = vi.x*vj.x + vi.y*vj.y + vi.z*vj.z + vi.w*vj.w;
    #pragma unroll
    for (int o = 32; o > 0; o >>= 1) {
        ssi += __shfl_xor(ssi, o);
        ssj += __shfl_xor(ssj, o);
        dij += __shfl_xor(dij, o);
    }
    float invi = 1.0f / fmaxf(sqrtf(ssi), 1e-8f);
    float invj = 1.0f / fmaxf(sqrtf(ssj), 1e-8f);
    float si = CSCALE * invi, sj = CSCALE * invj;
    ushort4 hi4, hj4;
    hi4.x = f2bf(vi.x * si); hi4.y = f2bf(vi.y * si);
    hi4.z = f2bf(vi.z * si); hi4.w = f2bf(vi.w * si);
    hj4.x = f2bf(vj.x * sj); hj4.y = f2bf(vj.y * sj);
    hj4.z = f2bf(vj.z * sj); hj4.w = f2bf(vj.w * sj);
    *reinterpret_cast<ushort4*>(zn + (size_t)pair * DDIM + lane * 4) = hi4;
    *reinterpret_cast<ushort4*>(zn + (size_t)(pair + B_ROWS) * DDIM + lane * 4) = hj4;
    if (lane == 0) simpos[pair] = 2.0f * dij * invi * invj;   // logits = cos/tau
    if (blockIdx.x < 256) parts[blockIdx.x * 256 + threadIdx.x] = 0.0f;  // zero 64K floats
}

// ---- kernel 2 body: 128 rows x 128 cols (2 x 64-col units), fully static ----
// 4 waves x 32 A-rows as 2 rowsets of 16 (a[2][8] = 64 VGPR). 16x16x32 MFMA:
// per subtile TWO independent 8-deep acc chains sharing each B-frag (ILP x2).
template<bool CROSS>
static __device__ __forceinline__ void sim_body(
        const unsigned short* __restrict__ zn, float* __restrict__ part,
        unsigned char* __restrict__ tile, float (* __restrict__ csum_lds)[128],
        int waveRow, int c0base) {
    int tid  = threadIdx.x;
    int wid  = tid >> 6;
    int lane = tid & 63;
    int l15  = lane & 15;
    int l4   = lane >> 4;

    // A fragments (16x16x32 layout: row = l15, k = m*32 + l4*8)
    short8 a[2][8];
    #pragma unroll
    for (int rs = 0; rs < 2; ++rs) {
        const unsigned short* ap = zn + (size_t)(waveRow + rs * 16 + l15) * DDIM;
        #pragma unroll
        for (int m = 0; m < 8; ++m)
            a[rs][m] = *reinterpret_cast<const short8*>(ap + m * 32 + l4 * 8);
    }

    float rsum[2][4] = {{0.f,0.f,0.f,0.f},{0.f,0.f,0.f,0.f}};

    #pragma unroll
    for (int ui = 0; ui < 2; ++ui) {
        int c0 = c0base + ui * 64;
        __syncthreads();   // protect tile before overwrite
        // stage 64 cols x 256 K bf16 = 32 KB, 4-bit XOR swizzle (ck ^ row&15);
        // two passes of 4 loads to cap in-flight register pressure.
        #pragma unroll
        for (int g = 0; g < 2; ++g) {
            uint4 t[4];
            #pragma unroll
            for (int p = 0; p < 4; ++p) {
                int id = (g * 4 + p) * 256 + tid;
                int tr = id >> 5, ck = id & 31;
                t[p] = *reinterpret_cast<const uint4*>(
                    zn + (size_t)(c0 + tr) * DDIM + ck * 8);
            }
            #pragma unroll
            for (int p = 0; p < 4; ++p) {
                int id = (g * 4 + p) * 256 + tid;
                int tr = id >> 5, ck = id & 31;
                *reinterpret_cast<uint4*>(tile + tr * 512 + ((ck ^ (tr & 15)) << 4)) = t[p];
            }
        }
        __syncthreads();

        #pragma unroll
        for (int sub = 0; sub < 4; ++sub) {
            // B row (= col) for this lane: sub*16 + l15; (row&15) == l15
            const unsigned char* bbase = tile + (size_t)(sub * 16 + l15) * 512;
            f32x4 acc0 = {0.f,0.f,0.f,0.f}, acc1 = {0.f,0.f,0.f,0.f};
            #pragma unroll
            for (int m = 0; m < 8; ++m) {
                short8 bf = *reinterpret_cast<const short8*>(
                    bbase + (((4 * m + l4) ^ l15) << 4));
                acc0 = __builtin_amdgcn_mfma_f32_16x16x32_bf16(a[0][m], bf, acc0, 0, 0, 0);
                acc1 = __builtin_amdgcn_mfma_f32_16x16x32_bf16(a[1][m], bf, acc1, 0, 0, 0);
            }
            int gcol = c0 + sub * 16 + l15;
            float cs = 0.0f;
            #pragma unroll
            for (int j = 0; j < 4; ++j) {
                float e0 = exp2f(acc0[j]);   // zn pre-scaled: acc = 2*log2e*cos
                float e1 = exp2f(acc1[j]);
                if (CROSS) {
                    int g0 = waveRow + l4 * 4 + j;        // rowset 0
                    e0 = (gcol > g0) ? e0 : 0.0f;
                    e1 = (gcol > g0 + 16) ? e1 : 0.0f;    // rowset 1
                }
                rsum[0][j] += e0;
                rsum[1][j] += e1;
                cs += e0 + e1;
            }
            cs += __shfl_xor(cs, 16);
            cs += __shfl_xor(cs, 32);
            if (lane < 16) csum_lds[wid][ui * 64 + sub * 16 + l15] = cs;
        }
    }

    // ---- flush rows: reduce across the 16 col-lanes, one atomic per row ----
    #pragma unroll
    for (int rs = 0; rs < 2; ++rs)
        #pragma unroll
        for (int j = 0; j < 4; ++j) {
            float s = rsum[rs][j];
            #pragma unroll
            for (int m = 8; m >= 1; m >>= 1) s += __shfl_xor(s, m);
            if (l15 == 0)
                atomicAdd(&part[waveRow + rs * 16 + l4 * 4 + j], s);
        }

    // ---- flush cols: sum 4 waves' slices, one atomic per col ----
    __syncthreads();
    if (tid < 128) {
        float s = csum_lds[0][tid] + csum_lds[1][tid]
                + csum_lds[2][tid] + csum_lds[3][tid];
        atomicAdd(&part[c0base + tid], s);
    }
}

// 2080 uniform blocks: strip s (64 strips of 128 rows) has 64-s blocks of 128
// cols starting at the diagonal; prefix(s) = 64s - s(s-1)/2. rel==0 => CROSS.
__global__ __launch_bounds__(256, 3) void sim_kernel(
        const unsigned short* __restrict__ zn, float* __restrict__ parts) {
    __shared__ __align__(16) unsigned char tile[64 * 512];   // 32 KB
    __shared__ float csum_lds[4][128];                       // 2 KB

    int b = blockIdx.x;
    int s = (int)(64.5f - sqrtf(4160.25f - 2.0f * (float)b));
    if (s < 0) s = 0;
    if (s > 63) s = 63;
    while (s > 0 && b < 64 * s - (s * (s - 1)) / 2) --s;
    while (b >= 64 * (s + 1) - ((s + 1) * s) / 2) ++s;
    int rel = b - (64 * s - (s * (s - 1)) / 2);

    int waveRow = s * 128 + (threadIdx.x >> 6) * 32;
    int c0base  = (s + rel) * 128;
    float* part = parts + (size_t)(b & (NPART - 1)) * NTOT;

    if (rel == 0) sim_body<true >(zn, part, tile, csum_lds, waveRow, c0base);
    else          sim_body<false>(zn, part, tile, csum_lds, waveRow, c0base);
}

// ---- kernel 3: loss partials; out zeroed by memset, atomicAdd final ----
__global__ __launch_bounds__(256) void finalize_kernel(
        const float* __restrict__ parts, const float* __restrict__ simpos,
        float* __restrict__ out) {
    __shared__ float red[4];
    int r = blockIdx.x * 512 + threadIdx.x;
    float acc = 0.0f;
    #pragma unroll
    for (int rr = 0; rr < 2; ++rr, r += 256) {
        float s = 0.0f;
        #pragma unroll
        for (int p = 0; p < NPART; ++p) s += parts[p * NTOT + r];
        acc += logf(s) - simpos[r & (B_ROWS - 1)];
    }
    #pragma unroll
    for (int o = 32; o > 0; o >>= 1) acc += __shfl_xor(acc, o);
    if ((threadIdx.x & 63) == 0) red[threadIdx.x >> 6] = acc;
    __syncthreads();
    if (threadIdx.x == 0)
        atomicAdd(out, (red[0] + red[1] + red[2] + red[3]) / (float)NTOT);
}

extern "C" void kernel_launch(void* const* d_in, const int* in_sizes, int n_in,
                              void* d_out, int out_size, void* d_ws, size_t ws_size,
                              hipStream_t stream) {
    const float* zi = (const float*)d_in[0];
    const float* zj = (const float*)d_in[1];
    float* out = (float*)d_out;

    unsigned short* zn = (unsigned short*)d_ws;                        // 4 MB
    float* parts  = (float*)((char*)d_ws + (size_t)NTOT * DDIM * 2);   // 256 KB
    float* simpos = parts + NPART * NTOT;                              // 16 KB

    hipMemsetAsync(out, 0, sizeof(float), stream);
    norm_kernel<<<B_ROWS / 4, 256, 0, stream>>>(zi, zj, zn, simpos, parts);
    sim_kernel<<<2080, 256, 0, stream>>>(zn, parts);
    finalize_kernel<<<16, 256, 0, stream>>>(parts, simpos, out);
}